// Round 7
// baseline (53.152 us; speedup 1.0000x reference)
//
#include <hip/hip_runtime.h>
#include <math.h>

// Segment mean via two-level counting sort.
//   pass1: per-chunk histogram over 391 node-buckets (dst>>8), int4 loads
//   pass2: column scan -> per-chunk offsets (choff), bucket totals
//   pass3: bucket base scan
//   pass4: block-local LDS sort storing (global_dest | packed_val) u64;
//          flat parallel writeout, run-contiguous global stores
//   pass5: per-bucket LDS packed-double reduce -> mean
// Fallback to packed-f64-atomic scatter if ws is too small.

#define PACK_MAGIC 4294967296.0   // 2^32
#define NB 391                    // ceil(100000 / 256)
#define BSHIFT 8
#define SNODES 256
#define NC 1024                   // chunks (= blocks) for hist/scatter
#define CMAX 3200                 // max edges per chunk staged in LDS
#define STHREADS 512              // scatter block size

__device__ __forceinline__ unsigned pack_pair(float v, int local) {
    unsigned b = __float_as_uint(v);
    b = (b + 0x80u) & 0xFFFFFF00u;           // round mantissa to 15 bits
    return b | (unsigned)local;
}

// ---------- sort-based path ----------

__global__ void hist_kernel(const int* __restrict__ dst, int* __restrict__ hist,
                            int n_edges, int chunk) {
    __shared__ int h[NB];
    for (int i = threadIdx.x; i < NB; i += blockDim.x) h[i] = 0;
    __syncthreads();
    int beg = blockIdx.x * chunk;
    int end = min(beg + chunk, n_edges);
    for (int i = beg + threadIdx.x * 4; i < end; i += blockDim.x * 4) {
        if (i + 3 < end) {
            int4 d4 = *reinterpret_cast<const int4*>(dst + i);
            atomicAdd(&h[d4.x >> BSHIFT], 1);
            atomicAdd(&h[d4.y >> BSHIFT], 1);
            atomicAdd(&h[d4.z >> BSHIFT], 1);
            atomicAdd(&h[d4.w >> BSHIFT], 1);
        } else {
            for (int j = i; j < end; ++j) atomicAdd(&h[dst[j] >> BSHIFT], 1);
        }
    }
    __syncthreads();
    for (int b = threadIdx.x; b < NB; b += blockDim.x)
        hist[(size_t)blockIdx.x * NB + b] = h[b];
}

// one block (64 threads) per bucket: exclusive scan down the chunk column.
__global__ void scan_col_kernel(const int* __restrict__ hist,
                                int* __restrict__ choff,
                                int* __restrict__ totals) {
    int b = blockIdx.x;
    int lane = threadIdx.x;  // 64
    int carry = 0;
    for (int c0 = 0; c0 < NC; c0 += 64) {
        int v = hist[(size_t)(c0 + lane) * NB + b];
        int s = v;
        for (int off = 1; off < 64; off <<= 1) {
            int t = __shfl_up(s, off);
            if (lane >= off) s += t;
        }
        choff[(size_t)(c0 + lane) * NB + b] = carry + (s - v);  // exclusive
        carry += __shfl(s, 63);
    }
    if (lane == 0) totals[b] = carry;
}

// one wave: exclusive scan over NB bucket totals -> base[NB+1]
__global__ void scan_base_kernel(const int* __restrict__ totals, int* __restrict__ base) {
    int lane = threadIdx.x;  // 64
    const int K = (NB + 63) / 64;  // 7
    int vals[7];
    int local = 0;
    for (int k = 0; k < K; ++k) {
        int idx = lane * K + k;
        int v = (idx < NB) ? totals[idx] : 0;
        vals[k] = v; local += v;
    }
    int s = local;
    for (int off = 1; off < 64; off <<= 1) {
        int t = __shfl_up(s, off);
        if (lane >= off) s += t;
    }
    int ex = s - local;
    int total = __shfl(s, 63);
    for (int k = 0; k < K; ++k) {
        int idx = lane * K + k;
        if (idx < NB) base[idx] = ex;
        ex += vals[k];
    }
    if (lane == 0) base[NB] = total;
}

// block-local counting sort into LDS u64 (dest<<32 | pack), flat writeout
__global__ void __launch_bounds__(STHREADS)
scatter_sort_kernel(const float* __restrict__ edge_x,
                    const int* __restrict__ dst,
                    const int* __restrict__ hist,
                    const int* __restrict__ choff,
                    const int* __restrict__ base,
                    unsigned* __restrict__ pairs,
                    int n_edges, int chunk) {
    __shared__ unsigned long long s_data[CMAX];
    __shared__ int h[NB];      // chunk bucket counts
    __shared__ int cnt[NB];    // local cursors (start at startp)
    __shared__ int delta[NB];  // gbase - startp  (dest = delta + pos)

    int tid = threadIdx.x;
    int blk = blockIdx.x;

    for (int b = tid; b < NB; b += blockDim.x) {
        h[b] = hist[(size_t)blk * NB + b];
        delta[b] = base[b] + choff[(size_t)blk * NB + b];  // gbase for now
    }
    __syncthreads();

    // wave 0: exclusive scan of h -> cnt (=startp); delta -= startp
    if (tid < 64) {
        int lane = tid;
        const int K = (NB + 63) / 64;  // 7
        int vals[7];
        int local = 0;
        for (int k = 0; k < K; ++k) {
            int idx = lane * K + k;
            int v = (idx < NB) ? h[idx] : 0;
            vals[k] = v; local += v;
        }
        int s = local;
        for (int off = 1; off < 64; off <<= 1) {
            int t = __shfl_up(s, off);
            if (lane >= off) s += t;
        }
        int ex = s - local;
        for (int k = 0; k < K; ++k) {
            int idx = lane * K + k;
            if (idx < NB) { cnt[idx] = ex; delta[idx] -= ex; }
            ex += vals[k];
        }
    }
    __syncthreads();

    int beg = blk * chunk;
    int end = min(beg + chunk, n_edges);
    int chunkN = end - beg;

    // staging: 4 consecutive edges per thread per iteration (int4 dst load)
    for (int i = beg + tid * 4; i < end; i += blockDim.x * 4) {
        if (i + 3 < end) {
            int4 d4 = *reinterpret_cast<const int4*>(dst + i);
            float v0 = edge_x[(size_t)(i + 0) * 8];
            float v1 = edge_x[(size_t)(i + 1) * 8];
            float v2 = edge_x[(size_t)(i + 2) * 8];
            float v3 = edge_x[(size_t)(i + 3) * 8];
            int b0 = d4.x >> BSHIFT;
            int p0 = atomicAdd(&cnt[b0], 1);
            s_data[p0] = ((unsigned long long)(unsigned)(delta[b0] + p0) << 32)
                       | pack_pair(v0, d4.x & (SNODES - 1));
            int b1 = d4.y >> BSHIFT;
            int p1 = atomicAdd(&cnt[b1], 1);
            s_data[p1] = ((unsigned long long)(unsigned)(delta[b1] + p1) << 32)
                       | pack_pair(v1, d4.y & (SNODES - 1));
            int b2 = d4.z >> BSHIFT;
            int p2 = atomicAdd(&cnt[b2], 1);
            s_data[p2] = ((unsigned long long)(unsigned)(delta[b2] + p2) << 32)
                       | pack_pair(v2, d4.z & (SNODES - 1));
            int b3 = d4.w >> BSHIFT;
            int p3 = atomicAdd(&cnt[b3], 1);
            s_data[p3] = ((unsigned long long)(unsigned)(delta[b3] + p3) << 32)
                       | pack_pair(v3, d4.w & (SNODES - 1));
        } else {
            for (int j = i; j < end; ++j) {
                int d = dst[j];
                float v = edge_x[(size_t)j * 8];
                int b = d >> BSHIFT;
                int p = atomicAdd(&cnt[b], 1);
                s_data[p] = ((unsigned long long)(unsigned)(delta[b] + p) << 32)
                          | pack_pair(v, d & (SNODES - 1));
            }
        }
    }
    __syncthreads();

    // writeout: flat parallel, dest embedded; stores are run-contiguous
    for (int p = tid; p < chunkN; p += blockDim.x) {
        unsigned long long v = s_data[p];
        pairs[v >> 32] = (unsigned)v;
    }
}

__global__ void reduce_kernel(const unsigned* __restrict__ pairs,
                              const int* __restrict__ base,
                              float* __restrict__ out, int n_nodes) {
    __shared__ double acc[SNODES];
    int b = blockIdx.x;
    for (int i = threadIdx.x; i < SNODES; i += blockDim.x) acc[i] = 0.0;
    __syncthreads();
    int beg = base[b], end = base[b + 1];
    for (int i = beg + threadIdx.x; i < end; i += blockDim.x) {
        unsigned p = pairs[i];
        float v = __uint_as_float(p & 0xFFFFFF00u);
        atomicAdd(&acc[p & 0xFFu], (double)v + PACK_MAGIC);
    }
    __syncthreads();
    int node0 = b << BSHIFT;
    for (int i = threadIdx.x; i < SNODES; i += blockDim.x) {
        int node = node0 + i;
        if (node < n_nodes) {
            double x = acc[i];
            double c = nearbyint(x * (1.0 / PACK_MAGIC));
            double s = x - c * PACK_MAGIC;
            out[node] = (c > 0.0) ? (float)(s / c) : 0.0f;
        }
    }
}

// ---------- fallback: packed-f64 atomic path ----------

__global__ void zero_ws_kernel(double* __restrict__ ws, int n) {
    int i = blockIdx.x * blockDim.x + threadIdx.x;
    int stride = gridDim.x * blockDim.x;
    for (; i < n; i += stride) ws[i] = 0.0;
}

__global__ void scatter_atomic_kernel(const float* __restrict__ edge_x,
                                      const int* __restrict__ dst,
                                      double* __restrict__ part,
                                      int n_edges, int n_nodes, int r_mask) {
    int t = blockIdx.x * blockDim.x + threadIdx.x;
    int basei = t * 4;
    double* my = part + (size_t)(blockIdx.x & r_mask) * (size_t)n_nodes;
    if (basei + 3 < n_edges) {
        int4 d4 = *reinterpret_cast<const int4*>(dst + basei);
        float v0 = edge_x[(size_t)(basei + 0) * 8];
        float v1 = edge_x[(size_t)(basei + 1) * 8];
        float v2 = edge_x[(size_t)(basei + 2) * 8];
        float v3 = edge_x[(size_t)(basei + 3) * 8];
        atomicAdd(&my[d4.x], (double)v0 + PACK_MAGIC);
        atomicAdd(&my[d4.y], (double)v1 + PACK_MAGIC);
        atomicAdd(&my[d4.z], (double)v2 + PACK_MAGIC);
        atomicAdd(&my[d4.w], (double)v3 + PACK_MAGIC);
    } else {
        for (int i = basei; i < n_edges; ++i) {
            float v = edge_x[(size_t)i * 8];
            atomicAdd(&my[dst[i]], (double)v + PACK_MAGIC);
        }
    }
}

__global__ void finalize_atomic_kernel(const double* __restrict__ part,
                                       float* __restrict__ out, int n_nodes, int R) {
    int i = blockIdx.x * blockDim.x + threadIdx.x;
    if (i >= n_nodes) return;
    double x = 0.0;
    for (int r = 0; r < R; ++r) x += part[(size_t)r * n_nodes + i];
    double c = nearbyint(x * (1.0 / PACK_MAGIC));
    double s = x - c * PACK_MAGIC;
    out[i] = (c > 0.0) ? (float)(s / c) : 0.0f;
}

// ---------- launch ----------

extern "C" void kernel_launch(void* const* d_in, const int* in_sizes, int n_in,
                              void* d_out, int out_size, void* d_ws, size_t ws_size,
                              hipStream_t stream) {
    const float* edge_x = (const float*)d_in[0];
    const int*   dst    = (const int*)d_in[1];
    float* out = (float*)d_out;

    const int n_nodes = out_size;        // 100000
    const int n_edges = in_sizes[1];     // 3200000

    size_t pairs_bytes = (size_t)n_edges * sizeof(unsigned);
    size_t hist_bytes  = (size_t)NC * NB * sizeof(int);
    size_t choff_bytes = hist_bytes;
    size_t base_bytes  = (size_t)(NB + 1) * sizeof(int);
    size_t tot_bytes   = (size_t)NB * sizeof(int);
    size_t need = pairs_bytes + hist_bytes + choff_bytes + base_bytes + tot_bytes;

    // chunk rounded up to multiple of 4 so int4 loads stay 16B-aligned
    int chunk = (((n_edges + NC - 1) / NC) + 3) & ~3;

    if (ws_size >= need && n_nodes <= NB * SNODES && chunk <= CMAX) {
        unsigned* pairs  = (unsigned*)d_ws;
        int*  hist   = (int*)((char*)d_ws + pairs_bytes);
        int*  choff  = (int*)((char*)hist + hist_bytes);
        int*  basep  = (int*)((char*)choff + choff_bytes);
        int*  totals = (int*)((char*)basep + base_bytes);

        hist_kernel<<<NC, 256, 0, stream>>>(dst, hist, n_edges, chunk);
        scan_col_kernel<<<NB, 64, 0, stream>>>(hist, choff, totals);
        scan_base_kernel<<<1, 64, 0, stream>>>(totals, basep);
        scatter_sort_kernel<<<NC, STHREADS, 0, stream>>>(edge_x, dst, hist, choff,
                                                         basep, pairs, n_edges, chunk);
        reduce_kernel<<<NB, 512, 0, stream>>>(pairs, basep, out, n_nodes);
    } else {
        int R = 1;
        while (R < 8 && (size_t)(R * 2) * (size_t)n_nodes * sizeof(double) <= ws_size) R *= 2;
        double* part = (double*)d_ws;
        {
            int n = R * n_nodes;
            int blocks = min((n + 255) / 256, 2048);
            zero_ws_kernel<<<blocks, 256, 0, stream>>>(part, n);
        }
        {
            int nthreads = (n_edges + 3) / 4;
            int blocks = (nthreads + 255) / 256;
            scatter_atomic_kernel<<<blocks, 256, 0, stream>>>(edge_x, dst, part,
                                                              n_edges, n_nodes, R - 1);
        }
        {
            int blocks = (n_nodes + 255) / 256;
            finalize_atomic_kernel<<<blocks, 256, 0, stream>>>(part, out, n_nodes, R);
        }
    }
}

// Round 8
// 52.312 us; speedup vs baseline: 1.0161x; 1.0161x over previous
//
#include <hip/hip_runtime.h>
#include <math.h>

// Segment mean via block-local counting sort + run-gather reduce.
//   K1: each block sorts its own 6252-edge chunk by node-bucket (dst>>8)
//       entirely in LDS, writes the sorted chunk DENSELY to its own region
//       of `pairs`, plus a per-chunk bucket-offset row `boff`.
//   K2: one block per bucket; thread t gathers chunk t's run for this
//       bucket (avg 16 consecutive u32), accumulates packed-double in LDS.
// All global writes dense/coalesced; the random permutation is absorbed by
// scattered (run-contiguous) READS in K2, which stream near-BW.
// Fallback to packed-f64-atomic scatter if ws is too small.

#define PACK_MAGIC 4294967296.0   // 2^32
#define NB 391                    // ceil(100000 / 256)
#define BSHIFT 8
#define SNODES 256
#define NC 512                    // chunks (= K1 blocks); also K2 threads/block
#define CMAXR 6400                // max chunkR staged in LDS (u32)
#define T1 512                    // K1 block size
#define T2 512                    // K2 block size (one chunk per thread)

__device__ __forceinline__ unsigned pack_pair(float v, int local) {
    unsigned b = __float_as_uint(v);
    b = (b + 0x80u) & 0xFFFFFF00u;           // round mantissa to 15 bits
    return b | (unsigned)local;
}

// K1: hist -> scan -> boff row -> LDS counting sort -> dense writeout
__global__ void __launch_bounds__(T1)
sort_kernel(const float* __restrict__ edge_x,
            const int* __restrict__ dst,
            unsigned* __restrict__ pairs,
            int* __restrict__ boff,
            int n_edges, int chunkR) {
    __shared__ unsigned s_data[CMAXR];
    __shared__ int h[NB];     // chunk bucket counts
    __shared__ int cnt[NB];   // cursors (start at exclusive-scan positions)

    int tid = threadIdx.x, blk = blockIdx.x;
    long beg = (long)blk * chunkR;
    long rem = (long)n_edges - beg;
    int chunkN = (rem < 0) ? 0 : (int)min((long)chunkR, rem);

    for (int b = tid; b < NB; b += T1) h[b] = 0;
    __syncthreads();

    // pass 1: histogram (dst read; stays L2-hot for pass 2)
    for (int i = tid; i < chunkN; i += T1)
        atomicAdd(&h[dst[beg + i] >> BSHIFT], 1);
    __syncthreads();

    // wave 0: exclusive scan h -> cnt
    if (tid < 64) {
        int lane = tid;
        const int K = (NB + 63) / 64;  // 7
        int vals[7];
        int local = 0;
        for (int k = 0; k < K; ++k) {
            int idx = lane * K + k;
            int v = (idx < NB) ? h[idx] : 0;
            vals[k] = v; local += v;
        }
        int s = local;
        for (int off = 1; off < 64; off <<= 1) {
            int t = __shfl_up(s, off);
            if (lane >= off) s += t;
        }
        int ex = s - local;
        for (int k = 0; k < K; ++k) {
            int idx = lane * K + k;
            if (idx < NB) cnt[idx] = ex;
            ex += vals[k];
        }
    }
    __syncthreads();

    // write boff row (exclusive starts + total) before cursors mutate
    {
        int* row = boff + (size_t)blk * (NB + 1);
        for (int b = tid; b < NB; b += T1) row[b] = cnt[b];
        if (tid == 0) row[NB] = chunkN;
    }
    __syncthreads();

    // pass 2: stage values into sorted LDS positions
    for (int i = tid; i < chunkN; i += T1) {
        int d = dst[beg + i];                    // L2-hot re-read
        float v = edge_x[(beg + i) * 8];
        int p = atomicAdd(&cnt[d >> BSHIFT], 1);
        s_data[p] = pack_pair(v, d & (SNODES - 1));
    }
    __syncthreads();

    // dense coalesced writeout (uint4)
    unsigned* outp = pairs + (size_t)blk * chunkR;
    for (int p = tid * 4; p < chunkN; p += T1 * 4) {
        if (p + 4 <= chunkN) {
            *reinterpret_cast<uint4*>(outp + p) =
                *reinterpret_cast<const uint4*>(&s_data[p]);
        } else {
            for (int q = p; q < chunkN; ++q) outp[q] = s_data[q];
        }
    }
}

// K2: one block per bucket; thread t gathers chunk t's run, LDS accumulate
__global__ void __launch_bounds__(T2)
reduce_kernel(const unsigned* __restrict__ pairs,
              const int* __restrict__ boff,
              float* __restrict__ out, int n_nodes, int chunkR) {
    __shared__ double acc[SNODES];
    int b = blockIdx.x, tid = threadIdx.x;
    for (int i = tid; i < SNODES; i += T2) acc[i] = 0.0;
    __syncthreads();

    for (int c = tid; c < NC; c += T2) {
        const int* row = boff + (size_t)c * (NB + 1);
        int s = row[b];
        int e = row[b + 1];
        const unsigned* src = pairs + (size_t)c * chunkR;
        for (int j = s; j < e; ++j) {
            unsigned p = src[j];
            float v = __uint_as_float(p & 0xFFFFFF00u);
            atomicAdd(&acc[p & 0xFFu], (double)v + PACK_MAGIC);
        }
    }
    __syncthreads();

    int node0 = b << BSHIFT;
    for (int i = tid; i < SNODES; i += T2) {
        int node = node0 + i;
        if (node < n_nodes) {
            double x = acc[i];
            double c2 = nearbyint(x * (1.0 / PACK_MAGIC));
            double s2 = x - c2 * PACK_MAGIC;
            out[node] = (c2 > 0.0) ? (float)(s2 / c2) : 0.0f;
        }
    }
}

// ---------- fallback: packed-f64 atomic path ----------

__global__ void zero_ws_kernel(double* __restrict__ ws, int n) {
    int i = blockIdx.x * blockDim.x + threadIdx.x;
    int stride = gridDim.x * blockDim.x;
    for (; i < n; i += stride) ws[i] = 0.0;
}

__global__ void scatter_atomic_kernel(const float* __restrict__ edge_x,
                                      const int* __restrict__ dst,
                                      double* __restrict__ part,
                                      int n_edges, int n_nodes, int r_mask) {
    int t = blockIdx.x * blockDim.x + threadIdx.x;
    int basei = t * 4;
    double* my = part + (size_t)(blockIdx.x & r_mask) * (size_t)n_nodes;
    if (basei + 3 < n_edges) {
        int4 d4 = *reinterpret_cast<const int4*>(dst + basei);
        float v0 = edge_x[(size_t)(basei + 0) * 8];
        float v1 = edge_x[(size_t)(basei + 1) * 8];
        float v2 = edge_x[(size_t)(basei + 2) * 8];
        float v3 = edge_x[(size_t)(basei + 3) * 8];
        atomicAdd(&my[d4.x], (double)v0 + PACK_MAGIC);
        atomicAdd(&my[d4.y], (double)v1 + PACK_MAGIC);
        atomicAdd(&my[d4.z], (double)v2 + PACK_MAGIC);
        atomicAdd(&my[d4.w], (double)v3 + PACK_MAGIC);
    } else {
        for (int i = basei; i < n_edges; ++i) {
            float v = edge_x[(size_t)i * 8];
            atomicAdd(&my[dst[i]], (double)v + PACK_MAGIC);
        }
    }
}

__global__ void finalize_atomic_kernel(const double* __restrict__ part,
                                       float* __restrict__ out, int n_nodes, int R) {
    int i = blockIdx.x * blockDim.x + threadIdx.x;
    if (i >= n_nodes) return;
    double x = 0.0;
    for (int r = 0; r < R; ++r) x += part[(size_t)r * n_nodes + i];
    double c = nearbyint(x * (1.0 / PACK_MAGIC));
    double s = x - c * PACK_MAGIC;
    out[i] = (c > 0.0) ? (float)(s / c) : 0.0f;
}

// ---------- launch ----------

extern "C" void kernel_launch(void* const* d_in, const int* in_sizes, int n_in,
                              void* d_out, int out_size, void* d_ws, size_t ws_size,
                              hipStream_t stream) {
    const float* edge_x = (const float*)d_in[0];
    const int*   dst    = (const int*)d_in[1];
    float* out = (float*)d_out;

    const int n_nodes = out_size;        // 100000
    const int n_edges = in_sizes[1];     // 3200000

    // chunk rounded to multiple of 4 (uint4 writeout alignment)
    int chunkR = (((n_edges + NC - 1) / NC) + 3) & ~3;

    size_t pairs_bytes = (size_t)NC * chunkR * sizeof(unsigned);
    size_t boff_bytes  = (size_t)NC * (NB + 1) * sizeof(int);
    size_t need = pairs_bytes + boff_bytes;

    if (ws_size >= need && n_nodes <= NB * SNODES && chunkR <= CMAXR) {
        unsigned* pairs = (unsigned*)d_ws;
        int* boff = (int*)((char*)d_ws + pairs_bytes);

        sort_kernel<<<NC, T1, 0, stream>>>(edge_x, dst, pairs, boff,
                                           n_edges, chunkR);
        reduce_kernel<<<NB, T2, 0, stream>>>(pairs, boff, out, n_nodes, chunkR);
    } else {
        int R = 1;
        while (R < 8 && (size_t)(R * 2) * (size_t)n_nodes * sizeof(double) <= ws_size) R *= 2;
        double* part = (double*)d_ws;
        {
            int n = R * n_nodes;
            int blocks = min((n + 255) / 256, 2048);
            zero_ws_kernel<<<blocks, 256, 0, stream>>>(part, n);
        }
        {
            int nthreads = (n_edges + 3) / 4;
            int blocks = (nthreads + 255) / 256;
            scatter_atomic_kernel<<<blocks, 256, 0, stream>>>(edge_x, dst, part,
                                                              n_edges, n_nodes, R - 1);
        }
        {
            int blocks = (n_nodes + 255) / 256;
            finalize_atomic_kernel<<<blocks, 256, 0, stream>>>(part, out, n_nodes, R);
        }
    }
}

// Round 9
// 50.926 us; speedup vs baseline: 1.0437x; 1.0272x over previous
//
#include <hip/hip_runtime.h>
#include <math.h>

// Segment mean via block-local counting sort + run-gather reduce.
//   K1: per-thread register prefetch of dst+edge_x (one exposed latency
//       round), LDS histogram + scan (boff written from scan regs),
//       LDS counting sort, dense uint4 writeout.
//   K2: one block per bucket; thread t gathers chunk t's run (avg 16
//       consecutive u32), accumulates packed-double in LDS.
// Fallback to packed-f64-atomic scatter if ws is too small.

#define PACK_MAGIC 4294967296.0   // 2^32
#define NB 391                    // ceil(100000 / 256)
#define BSHIFT 8
#define SNODES 256
#define NC 512                    // chunks (= K1 blocks; K2 threads)
#define CMAXR 6400                // max chunkR staged in LDS (u32)
#define T1 1024                   // K1 block size (16 waves)
#define EPT 7                     // edges per thread: chunkR <= T1*EPT
#define T2 512                    // K2 block size (one chunk per thread)

__device__ __forceinline__ unsigned pack_pair(float v, int local) {
    unsigned b = __float_as_uint(v);
    b = (b + 0x80u) & 0xFFFFFF00u;           // round mantissa to 15 bits
    return b | (unsigned)local;
}

// K1: reg prefetch -> hist -> scan(+boff store) -> LDS sort -> dense writeout
__global__ void __launch_bounds__(T1)
sort_kernel(const float* __restrict__ edge_x,
            const int* __restrict__ dst,
            unsigned* __restrict__ pairs,
            int* __restrict__ boff,
            int n_edges, int chunkR) {
    __shared__ unsigned s_data[CMAXR];
    __shared__ int h[NB];     // chunk bucket counts
    __shared__ int cnt[NB];   // cursors (start at exclusive-scan positions)

    int tid = threadIdx.x, blk = blockIdx.x;
    long beg = (long)blk * chunkR;
    long rem = (long)n_edges - beg;
    int chunkN = (rem < 0) ? 0 : (int)min((long)chunkR, rem);

    // prefetch ALL this thread's edges into registers (deep ILP, one round)
    int   rd[EPT];
    float rv[EPT];
#pragma unroll
    for (int k = 0; k < EPT; ++k) {
        int i = tid + k * T1;
        bool ok = (i < chunkN);
        rd[k] = ok ? dst[beg + i] : -1;
        rv[k] = ok ? edge_x[(size_t)(beg + i) * 8] : 0.0f;
    }

    for (int b = tid; b < NB; b += T1) h[b] = 0;
    __syncthreads();

    // histogram from registers (waits only on rd loads)
#pragma unroll
    for (int k = 0; k < EPT; ++k)
        if (rd[k] >= 0) atomicAdd(&h[rd[k] >> BSHIFT], 1);
    __syncthreads();

    // wave 0: exclusive scan h -> cnt, store boff row from registers
    if (tid < 64) {
        int lane = tid;
        const int K = (NB + 63) / 64;  // 7
        int vals[7];
        int local = 0;
#pragma unroll
        for (int k = 0; k < K; ++k) {
            int idx = lane * K + k;
            int v = (idx < NB) ? h[idx] : 0;
            vals[k] = v; local += v;
        }
        int s = local;
        for (int off = 1; off < 64; off <<= 1) {
            int t = __shfl_up(s, off);
            if (lane >= off) s += t;
        }
        int ex = s - local;
        int* row = boff + (size_t)blk * (NB + 1);
#pragma unroll
        for (int k = 0; k < K; ++k) {
            int idx = lane * K + k;
            if (idx < NB) { cnt[idx] = ex; row[idx] = ex; }
            ex += vals[k];
        }
        if (lane == 0) row[NB] = chunkN;
    }
    __syncthreads();

    // stage into sorted LDS positions (edge_x latency already hidden)
#pragma unroll
    for (int k = 0; k < EPT; ++k) {
        if (rd[k] >= 0) {
            int b = rd[k] >> BSHIFT;
            int p = atomicAdd(&cnt[b], 1);
            s_data[p] = pack_pair(rv[k], rd[k] & (SNODES - 1));
        }
    }
    __syncthreads();

    // dense coalesced writeout (uint4)
    unsigned* outp = pairs + (size_t)blk * chunkR;
    for (int p = tid * 4; p < chunkN; p += T1 * 4) {
        if (p + 4 <= chunkN) {
            *reinterpret_cast<uint4*>(outp + p) =
                *reinterpret_cast<const uint4*>(&s_data[p]);
        } else {
            for (int q = p; q < chunkN; ++q) outp[q] = s_data[q];
        }
    }
}

// K2: one block per bucket; thread t gathers chunk t's run, LDS accumulate
__global__ void __launch_bounds__(T2)
reduce_kernel(const unsigned* __restrict__ pairs,
              const int* __restrict__ boff,
              float* __restrict__ out, int n_nodes, int chunkR) {
    __shared__ double acc[SNODES];
    int b = blockIdx.x, tid = threadIdx.x;
    for (int i = tid; i < SNODES; i += T2) acc[i] = 0.0;
    __syncthreads();

    for (int c = tid; c < NC; c += T2) {
        const int* row = boff + (size_t)c * (NB + 1);
        int s = row[b];
        int e = row[b + 1];
        const unsigned* src = pairs + (size_t)c * chunkR;
        for (int j = s; j < e; ++j) {
            unsigned p = src[j];
            float v = __uint_as_float(p & 0xFFFFFF00u);
            atomicAdd(&acc[p & 0xFFu], (double)v + PACK_MAGIC);
        }
    }
    __syncthreads();

    int node0 = b << BSHIFT;
    for (int i = tid; i < SNODES; i += T2) {
        int node = node0 + i;
        if (node < n_nodes) {
            double x = acc[i];
            double c2 = nearbyint(x * (1.0 / PACK_MAGIC));
            double s2 = x - c2 * PACK_MAGIC;
            out[node] = (c2 > 0.0) ? (float)(s2 / c2) : 0.0f;
        }
    }
}

// ---------- fallback: packed-f64 atomic path ----------

__global__ void zero_ws_kernel(double* __restrict__ ws, int n) {
    int i = blockIdx.x * blockDim.x + threadIdx.x;
    int stride = gridDim.x * blockDim.x;
    for (; i < n; i += stride) ws[i] = 0.0;
}

__global__ void scatter_atomic_kernel(const float* __restrict__ edge_x,
                                      const int* __restrict__ dst,
                                      double* __restrict__ part,
                                      int n_edges, int n_nodes, int r_mask) {
    int t = blockIdx.x * blockDim.x + threadIdx.x;
    int basei = t * 4;
    double* my = part + (size_t)(blockIdx.x & r_mask) * (size_t)n_nodes;
    if (basei + 3 < n_edges) {
        int4 d4 = *reinterpret_cast<const int4*>(dst + basei);
        float v0 = edge_x[(size_t)(basei + 0) * 8];
        float v1 = edge_x[(size_t)(basei + 1) * 8];
        float v2 = edge_x[(size_t)(basei + 2) * 8];
        float v3 = edge_x[(size_t)(basei + 3) * 8];
        atomicAdd(&my[d4.x], (double)v0 + PACK_MAGIC);
        atomicAdd(&my[d4.y], (double)v1 + PACK_MAGIC);
        atomicAdd(&my[d4.z], (double)v2 + PACK_MAGIC);
        atomicAdd(&my[d4.w], (double)v3 + PACK_MAGIC);
    } else {
        for (int i = basei; i < n_edges; ++i) {
            float v = edge_x[(size_t)i * 8];
            atomicAdd(&my[dst[i]], (double)v + PACK_MAGIC);
        }
    }
}

__global__ void finalize_atomic_kernel(const double* __restrict__ part,
                                       float* __restrict__ out, int n_nodes, int R) {
    int i = blockIdx.x * blockDim.x + threadIdx.x;
    if (i >= n_nodes) return;
    double x = 0.0;
    for (int r = 0; r < R; ++r) x += part[(size_t)r * n_nodes + i];
    double c = nearbyint(x * (1.0 / PACK_MAGIC));
    double s = x - c * PACK_MAGIC;
    out[i] = (c > 0.0) ? (float)(s / c) : 0.0f;
}

// ---------- launch ----------

extern "C" void kernel_launch(void* const* d_in, const int* in_sizes, int n_in,
                              void* d_out, int out_size, void* d_ws, size_t ws_size,
                              hipStream_t stream) {
    const float* edge_x = (const float*)d_in[0];
    const int*   dst    = (const int*)d_in[1];
    float* out = (float*)d_out;

    const int n_nodes = out_size;        // 100000
    const int n_edges = in_sizes[1];     // 3200000

    // chunk rounded to multiple of 4 (uint4 writeout alignment)
    int chunkR = (((n_edges + NC - 1) / NC) + 3) & ~3;

    size_t pairs_bytes = (size_t)NC * chunkR * sizeof(unsigned);
    size_t boff_bytes  = (size_t)NC * (NB + 1) * sizeof(int);
    size_t need = pairs_bytes + boff_bytes;

    if (ws_size >= need && n_nodes <= NB * SNODES &&
        chunkR <= CMAXR && chunkR <= T1 * EPT) {
        unsigned* pairs = (unsigned*)d_ws;
        int* boff = (int*)((char*)d_ws + pairs_bytes);

        sort_kernel<<<NC, T1, 0, stream>>>(edge_x, dst, pairs, boff,
                                           n_edges, chunkR);
        reduce_kernel<<<NB, T2, 0, stream>>>(pairs, boff, out, n_nodes, chunkR);
    } else {
        int R = 1;
        while (R < 8 && (size_t)(R * 2) * (size_t)n_nodes * sizeof(double) <= ws_size) R *= 2;
        double* part = (double*)d_ws;
        {
            int n = R * n_nodes;
            int blocks = min((n + 255) / 256, 2048);
            zero_ws_kernel<<<blocks, 256, 0, stream>>>(part, n);
        }
        {
            int nthreads = (n_edges + 3) / 4;
            int blocks = (nthreads + 255) / 256;
            scatter_atomic_kernel<<<blocks, 256, 0, stream>>>(edge_x, dst, part,
                                                              n_edges, n_nodes, R - 1);
        }
        {
            int blocks = (n_nodes + 255) / 256;
            finalize_atomic_kernel<<<blocks, 256, 0, stream>>>(part, out, n_nodes, R);
        }
    }
}